// Round 7
// baseline (334.987 us; speedup 1.0000x reference)
//
#include <hip/hip_runtime.h>
#include <hip/hip_bf16.h>
#include <cstdint>
#include <cstddef>

#define TT 2048      // tokens (b*t)
#define DD 1024      // d
#define HH 2048      // h
#define NE 16        // experts
#define WM128 48     // max (expert, 128-row block) work items
#define WM64  80     // max (expert, 64-row block) work items
#define PSTR 528     // panel stride in u16: [32 k][16 n] + 16 skew

typedef __bf16 bf16x8 __attribute__((ext_vector_type(8)));
typedef float f32x4 __attribute__((ext_vector_type(4)));
typedef __attribute__((address_space(3))) const unsigned short* lds_cu16;

__device__ __forceinline__ unsigned short f2bf(float f) {
  union { float f; unsigned u; } v; v.f = f;
  unsigned r = (v.u + 0x7FFFu + ((v.u >> 16) & 1u)) >> 16;  // RNE
  return (unsigned short)r;
}
__device__ __forceinline__ float bf2f(unsigned short s) {
  union { unsigned u; float f; } v; v.u = ((unsigned)s) << 16;
  return v.f;
}

__device__ __forceinline__ void gl_lds16(const void* g, void* l) {
  __builtin_amdgcn_global_load_lds(
      (const __attribute__((address_space(1))) unsigned int*)g,
      (__attribute__((address_space(3))) unsigned int*)l, 16, 0, 0);
}

// Two transpose-reads building a K-contiguous B-frag from a [32 k][16 n] panel.
// Per-lane base (cA*lr + cK*kg) is probed at runtime (k_probe).
__device__ __forceinline__ bf16x8 trfrag(const unsigned short* p) {
  lds_cu16 lp = (lds_cu16)p;
  unsigned long long a, b;
  asm volatile("ds_read_b64_tr_b16 %0, %1 offset:0"   : "=v"(a) : "v"(lp) : "memory");
  asm volatile("ds_read_b64_tr_b16 %0, %1 offset:128" : "=v"(b) : "v"(lp) : "memory");
  union { unsigned long long q[2]; bf16x8 v; } u;
  u.q[0] = a; u.q[1] = b;
  return u.v;
}

// ---------------- probe: resolve ds_read_b64_tr_b16 addressing semantics ----------------
// Fills panel0 with value k*64+n at the production layout position [k*16 + n],
// then tests candidate per-lane base recipes. pm = {mode, cA, cK}; mode 3 = fallback.
__global__ void k_probe(int* __restrict__ pm) {
  __shared__ unsigned short lds[1024];
  const int l = threadIdx.x & 63;
  for (int i = threadIdx.x; i < 1024; i += 64) lds[i] = 0xDEAD;
  __syncthreads();
  for (int i = threadIdx.x; i < 512; i += 64) {
    int k = i >> 4, n = i & 15;
    lds[k * 16 + n] = (unsigned short)(k * 64 + n);
  }
  __syncthreads();
  const int lr = l & 15, kg = l >> 4;
  const int candA[3] = {1, 0, 0};
  const int candK[3] = {128, 64, 128};
  int found = -1, fca = 0, fck = 0;
  #pragma unroll
  for (int c = 0; c < 3; ++c) {
    int base = candA[c] * lr + candK[c] * kg;
    unsigned long long a, b;
    lds_cu16 lp = (lds_cu16)&lds[base];
    asm volatile("ds_read_b64_tr_b16 %0, %1 offset:0"   : "=v"(a) : "v"(lp) : "memory");
    asm volatile("ds_read_b64_tr_b16 %0, %1 offset:128" : "=v"(b) : "v"(lp) : "memory");
    asm volatile("s_waitcnt lgkmcnt(0)" ::: "memory");
    bool ok = true;
    #pragma unroll
    for (int j = 0; j < 4; ++j) {
      unsigned short va = (unsigned short)(a >> (16 * j));
      unsigned short vb = (unsigned short)(b >> (16 * j));
      ok = ok && (va == (unsigned short)((8 * kg + j) * 64 + lr));
      ok = ok && (vb == (unsigned short)((8 * kg + 4 + j) * 64 + lr));
    }
    bool allok = __all(ok);
    if (allok && found < 0) { found = c; fca = candA[c]; fck = candK[c]; }
  }
  if (threadIdx.x == 0) {
    pm[0] = (found < 0) ? 3 : found;
    pm[1] = fca; pm[2] = fck;
  }
}

// ---------------- x fp32 -> bf16 ----------------
__global__ __launch_bounds__(256) void k_cvt_x(const float* __restrict__ x,
                                               unsigned short* __restrict__ xbf) {
  int i = blockIdx.x * 256 + threadIdx.x;
  const float4* p = reinterpret_cast<const float4*>(x) + (size_t)i * 2;
  float4 a = p[0], b = p[1];
  ushort4 o0 = { f2bf(a.x), f2bf(a.y), f2bf(a.z), f2bf(a.w) };
  ushort4 o1 = { f2bf(b.x), f2bf(b.y), f2bf(b.z), f2bf(b.w) };
  reinterpret_cast<ushort4*>(xbf)[(size_t)i * 2]     = o0;
  reinterpret_cast<ushort4*>(xbf)[(size_t)i * 2 + 1] = o1;
}

// ---------------- fallback transpose (guarded: runs only if mode==3) ----------------
__global__ __launch_bounds__(256) void k_trans(const float* __restrict__ src0,
                                               const float* __restrict__ src1,
                                               unsigned short* __restrict__ dst0,
                                               unsigned short* __restrict__ dst1,
                                               int R, int C, const int* __restrict__ pm) {
  if (pm[0] != 3) return;
  __shared__ unsigned short st[64][68];
  const int e = blockIdx.z & 15;
  const int m = blockIdx.z >> 4;
  const float* src = m ? src1 : src0;
  unsigned short* dst = m ? dst1 : dst0;
  const int c0 = blockIdx.x * 64, r0 = blockIdx.y * 64;
  const float* s = src + (size_t)e * R * C;
  unsigned short* d = dst + (size_t)e * R * C;
  const int tid = threadIdx.x;
  #pragma unroll
  for (int p = 0; p < 4; ++p) {
    int r = p * 16 + (tid >> 4);
    int c = (tid & 15) * 4;
    float4 v = *reinterpret_cast<const float4*>(s + (size_t)(r0 + r) * C + c0 + c);
    ushort4 o = { f2bf(v.x), f2bf(v.y), f2bf(v.z), f2bf(v.w) };
    *reinterpret_cast<ushort4*>(&st[r][c]) = o;
  }
  __syncthreads();
  #pragma unroll
  for (int q = 0; q < 4; ++q) {
    int c = q * 16 + (tid >> 4);
    int r4 = (tid & 15) * 4;
    ushort4 o = { st[r4][c], st[r4 + 1][c], st[r4 + 2][c], st[r4 + 3][c] };
    *reinterpret_cast<ushort4*>(d + (size_t)(c0 + c) * R + r0 + r4) = o;
  }
}

// ---------------- router + top-2 + bucketing ----------------
__global__ __launch_bounds__(256) void k_router(
    const float* __restrict__ x, const float* __restrict__ rw,
    const float* __restrict__ rb, int* __restrict__ cnt,
    int* __restrict__ list_tok, int* __restrict__ rec,
    float* __restrict__ wrec) {
  const int t = blockIdx.x;
  __shared__ float xs[DD];
  __shared__ float part[256];
  __shared__ float sc[NE];
  const float* xr = x + (size_t)t * DD;
  for (int i = threadIdx.x; i < DD; i += 256) xs[i] = xr[i];
  __syncthreads();
  const int e = threadIdx.x >> 4, j = threadIdx.x & 15;
  const float* w = rw + (size_t)e * DD;
  float s = 0.f;
  for (int i = j; i < DD; i += 16) s += xs[i] * w[i];
  part[threadIdx.x] = s;
  __syncthreads();
  if (threadIdx.x < NE) {
    float v = rb[threadIdx.x];
    #pragma unroll
    for (int q = 0; q < 16; ++q) v += part[threadIdx.x * 16 + q];
    sc[threadIdx.x] = v;
  }
  __syncthreads();
  if (threadIdx.x == 0) {
    int e1 = 0; float v1 = sc[0];
    #pragma unroll
    for (int q = 1; q < NE; ++q) { if (sc[q] > v1) { v1 = sc[q]; e1 = q; } }
    int e2 = -1; float v2 = -3.4e38f;
    #pragma unroll
    for (int q = 0; q < NE; ++q) {
      if (q != e1 && sc[q] > v2) { v2 = sc[q]; e2 = q; }
    }
    float ex = expf(v2 - v1);
    float w1 = 1.f / (1.f + ex);
    float w2 = ex / (1.f + ex);
    int p1 = atomicAdd(&cnt[e1], 1);
    int p2 = atomicAdd(&cnt[e2], 1);
    list_tok[e1 * TT + p1] = t;
    list_tok[e2 * TT + p2] = t;
    rec[t * 4 + 0] = e1; rec[t * 4 + 1] = p1;
    rec[t * 4 + 2] = e2; rec[t * 4 + 3] = p2;
    wrec[t * 2 + 0] = w1; wrec[t * 2 + 1] = w2;
  }
}

// ---------------- work-table builder ----------------
__global__ void k_sched(const int* __restrict__ cnt, int* __restrict__ work128,
                        int* __restrict__ work64, int* __restrict__ woff) {
  if (threadIdx.x == 0) {
    int o = 0, n1 = 0, n2 = 0;
    for (int e = 0; e < NE; ++e) {
      int ce = cnt[e];
      int a = (ce + 127) >> 7;
      for (int mb = 0; mb < a; ++mb) { work128[n1 * 2] = e; work128[n1 * 2 + 1] = mb; ++n1; }
      int b = (ce + 63) >> 6;
      for (int mb = 0; mb < b; ++mb) { work64[n2 * 2] = e; work64[n2 * 2 + 1] = mb; ++n2; }
      woff[e] = o; o += ce;
    }
    for (int q = n1; q < WM128; ++q) { work128[q * 2] = -1; work128[q * 2 + 1] = 0; }
    for (int q = n2; q < WM64; ++q)  { work64[q * 2] = -1;  work64[q * 2 + 1] = 0; }
  }
}

// ---------------- up GEMMs (mag,freq) + activation ----------------
// BM=128, BN=64, BK=32. A: bf16 gl_lds. B: fused fp32 path (tr-read) or
// fallback pre-transposed bf16 path, selected by probe result.
__global__ __launch_bounds__(256, 3) void k_up(
    const unsigned short* __restrict__ xbf,
    const float* __restrict__ bmag, const float* __restrict__ bfreq,
    const unsigned short* __restrict__ wmT, const unsigned short* __restrict__ wfT,
    const float* __restrict__ bphase,
    const int* __restrict__ cnt, const int* __restrict__ list_tok,
    const int* __restrict__ work, const int* __restrict__ woff,
    const int* __restrict__ pm,
    unsigned short* __restrict__ hid) {
  const int e = work[blockIdx.x * 2 + 0];
  if (e < 0) return;
  const int mt = work[blockIdx.x * 2 + 1];
  const int nt = blockIdx.y;
  const int ce = cnt[e];
  const int off = woff[e];
  const int tmode = pm[0];
  __shared__ unsigned short As[2][128][32];       // 16 KB
  __shared__ unsigned short Bst[2][2][4 * PSTR];  // ~16.9 KB (fused panels / fallback [64][32]x2)
  __shared__ int toks[128];
  const int tid = threadIdx.x;
  if (tid < 128) {
    int r = mt * 128 + tid;
    toks[tid] = list_tok[e * TT + (r < ce ? r : ce - 1)];
  }
  __syncthreads();
  const int w = tid >> 6, l = tid & 63;
  // A staging (common): 2 chunks/thread, source-side XOR chunk swizzle
  size_t abase[2]; int aoff[2];
  #pragma unroll
  for (int p = 0; p < 2; ++p) {
    int row = p * 64 + w * 16 + (l >> 2);
    int g = (l & 3) ^ ((row >> 1) & 3);
    abase[p] = (size_t)toks[row] * DD + g * 8;
    aoff[p] = (p * 256 + w * 64 + l) * 8;
  }
  const int n0 = nt * 64;
  const int wm = (w >> 1) * 64, wn = (w & 1) * 32;
  const int lr = l & 15, kg = l >> 4;
  const f32x4 zero = {0.f, 0.f, 0.f, 0.f};
  f32x4 accM[4][2], accF[4][2];
  #pragma unroll
  for (int a = 0; a < 4; ++a)
    #pragma unroll
    for (int b = 0; b < 2; ++b) { accM[a][b] = zero; accF[a][b] = zero; }

  if (tmode < 3) {
    // ---------- fused path: fp32 weights, reg-stage -> cvt -> panels -> tr-read ----------
    const int cA = pm[1], cK = pm[2];
    const float* srcM = bmag  + (size_t)e * DD * HH + n0;
    const float* srcF = bfreq + (size_t)e * DD * HH + n0;
    int bgl[2], bwr[2];
    #pragma unroll
    for (int s = 0; s < 2; ++s) {
      int idx = s * 256 + tid;
      int k = idx >> 4;
      bgl[s] = k * HH + (idx & 15) * 4;
      bwr[s] = ((idx >> 2) & 3) * PSTR + k * 16 + (idx & 3) * 4;
    }
    const int tbadd = cA * lr + cK * kg;
    const int tb0 = ((w & 1) * 2) * PSTR + tbadd;
    const int tb1 = tb0 + PSTR;
    float4 rm[2], rf[2];
    #pragma unroll
    for (int s = 0; s < 2; ++s) {
      rm[s] = *reinterpret_cast<const float4*>(srcM + bgl[s]);
      rf[s] = *reinterpret_cast<const float4*>(srcF + bgl[s]);
    }
    #pragma unroll
    for (int p = 0; p < 2; ++p) gl_lds16(xbf + abase[p], &As[0][0][0] + aoff[p]);
    #pragma unroll
    for (int s = 0; s < 2; ++s) {
      ushort4 om = { f2bf(rm[s].x), f2bf(rm[s].y), f2bf(rm[s].z), f2bf(rm[s].w) };
      ushort4 of = { f2bf(rf[s].x), f2bf(rf[s].y), f2bf(rf[s].z), f2bf(rf[s].w) };
      *reinterpret_cast<ushort4*>(&Bst[0][0][bwr[s]]) = om;
      *reinterpret_cast<ushort4*>(&Bst[0][1][bwr[s]]) = of;
    }
    __syncthreads();
    int buf = 0;
    for (int kt = 0; kt < DD / 32; ++kt) {
      const int nxt = kt + 1;
      const bool more = nxt < DD / 32;
      if (more) {
        const size_t g = (size_t)nxt * (32 * HH);
        #pragma unroll
        for (int s = 0; s < 2; ++s) {
          rm[s] = *reinterpret_cast<const float4*>(srcM + g + bgl[s]);
          rf[s] = *reinterpret_cast<const float4*>(srcF + g + bgl[s]);
        }
        #pragma unroll
        for (int p = 0; p < 2; ++p)
          gl_lds16(xbf + abase[p] + nxt * 32, &As[buf ^ 1][0][0] + aoff[p]);
      }
      bf16x8 av[4];
      #pragma unroll
      for (int fm = 0; fm < 4; ++fm) {
        int row = wm + fm * 16 + lr;
        int c = kg ^ ((row >> 1) & 3);
        av[fm] = *reinterpret_cast<const bf16x8*>(&As[buf][row][c * 8]);
      }
      bf16x8 bmv0 = trfrag(&Bst[buf][0][0] + tb0);
      bf16x8 bmv1 = trfrag(&Bst[buf][0][0] + tb1);
      bf16x8 bfv0 = trfrag(&Bst[buf][1][0] + tb0);
      bf16x8 bfv1 = trfrag(&Bst[buf][1][0] + tb1);
      asm volatile("s_waitcnt lgkmcnt(0)" ::: "memory");
      __builtin_amdgcn_sched_barrier(0);
      #pragma unroll
      for (int fm = 0; fm < 4; ++fm) {
        accM[fm][0] = __builtin_amdgcn_mfma_f32_16x16x32_bf16(av[fm], bmv0, accM[fm][0], 0, 0, 0);
        accM[fm][1] = __builtin_amdgcn_mfma_f32_16x16x32_bf16(av[fm], bmv1, accM[fm][1], 0, 0, 0);
        accF[fm][0] = __builtin_amdgcn_mfma_f32_16x16x32_bf16(av[fm], bfv0, accF[fm][0], 0, 0, 0);
        accF[fm][1] = __builtin_amdgcn_mfma_f32_16x16x32_bf16(av[fm], bfv1, accF[fm][1], 0, 0, 0);
      }
      if (more) {
        #pragma unroll
        for (int s = 0; s < 2; ++s) {
          ushort4 om = { f2bf(rm[s].x), f2bf(rm[s].y), f2bf(rm[s].z), f2bf(rm[s].w) };
          ushort4 of = { f2bf(rf[s].x), f2bf(rf[s].y), f2bf(rf[s].z), f2bf(rf[s].w) };
          *reinterpret_cast<ushort4*>(&Bst[buf ^ 1][0][bwr[s]]) = om;
          *reinterpret_cast<ushort4*>(&Bst[buf ^ 1][1][bwr[s]]) = of;
        }
      }
      __syncthreads();
      buf ^= 1;
    }
  } else {
    // ---------- fallback path: pre-transposed bf16 weights via gl_lds ----------
    const int nrow = tid >> 2;
    const int gB = (tid & 3) ^ ((nrow >> 1) & 3);
    const size_t bbase = ((size_t)e * HH + n0 + nrow) * DD + gB * 8;
    const int boff = tid * 8;
    #pragma unroll
    for (int p = 0; p < 2; ++p) gl_lds16(xbf + abase[p], &As[0][0][0] + aoff[p]);
    gl_lds16(wmT + bbase, &Bst[0][0][0] + boff);
    gl_lds16(wfT + bbase, &Bst[0][1][0] + boff);
    __syncthreads();
    int buf = 0;
    for (int kt = 0; kt < DD / 32; ++kt) {
      const int nxt = kt + 1;
      if (nxt < DD / 32) {
        #pragma unroll
        for (int p = 0; p < 2; ++p)
          gl_lds16(xbf + abase[p] + nxt * 32, &As[buf ^ 1][0][0] + aoff[p]);
        gl_lds16(wmT + bbase + nxt * 32, &Bst[buf ^ 1][0][0] + boff);
        gl_lds16(wfT + bbase + nxt * 32, &Bst[buf ^ 1][1][0] + boff);
      }
      bf16x8 av[4], bmv[2], bfv[2];
      #pragma unroll
      for (int fm = 0; fm < 4; ++fm) {
        int row = wm + fm * 16 + lr;
        int c = kg ^ ((row >> 1) & 3);
        av[fm] = *reinterpret_cast<const bf16x8*>(&As[buf][row][c * 8]);
      }
      #pragma unroll
      for (int fn = 0; fn < 2; ++fn) {
        int row = wn + fn * 16 + lr;
        int c = kg ^ ((row >> 1) & 3);
        bmv[fn] = *reinterpret_cast<const bf16x8*>(&Bst[buf][0][row * 32 + c * 8]);
        bfv[fn] = *reinterpret_cast<const bf16x8*>(&Bst[buf][1][row * 32 + c * 8]);
      }
      #pragma unroll
      for (int fm = 0; fm < 4; ++fm)
        #pragma unroll
        for (int fn = 0; fn < 2; ++fn) {
          accM[fm][fn] = __builtin_amdgcn_mfma_f32_16x16x32_bf16(av[fm], bmv[fn], accM[fm][fn], 0, 0, 0);
          accF[fm][fn] = __builtin_amdgcn_mfma_f32_16x16x32_bf16(av[fm], bfv[fn], accF[fm][fn], 0, 0, 0);
        }
      __syncthreads();
      buf ^= 1;
    }
  }
  // ---------- epilogue (common) ----------
  #pragma unroll
  for (int fn = 0; fn < 2; ++fn) {
    const int ng = n0 + wn + fn * 16 + lr;
    const float ph = bphase[e * HH + ng] + 0.1f;
    #pragma unroll
    for (int fm = 0; fm < 4; ++fm) {
      #pragma unroll
      for (int jj = 0; jj < 4; ++jj) {
        int m = mt * 128 + wm + fm * 16 + kg * 4 + jj;
        if (m < ce) {
          float mv = accM[fm][fn][jj];
          float fv = accF[fm][fn][jj];
          float exn = __expf(-fabsf(fv));
          float sp = fmaxf(fv, 0.f) + __logf(1.f + exn);   // stable softplus
          float t2 = __expf(2.f * mv);
          float th = 1.f - 2.f / (t2 + 1.f);               // tanh
          float hv = th * __cosf(sp + ph);
          hid[(size_t)(off + m) * HH + ng] = f2bf(hv);
        }
      }
    }
  }
}

// ---------------- down GEMM: BM=64, BN=64, BK=32, waves 2x2 of 32x32 ----------------
__global__ __launch_bounds__(256, 4) void k_down(
    const unsigned short* __restrict__ hid,
    const float* __restrict__ bdown,
    const unsigned short* __restrict__ wdT,
    const int* __restrict__ cnt,
    const int* __restrict__ work, const int* __restrict__ woff,
    const int* __restrict__ pm,
    unsigned short* __restrict__ op) {
  const int e = work[blockIdx.x * 2 + 0];
  if (e < 0) return;
  const int mt = work[blockIdx.x * 2 + 1];
  const int nt = blockIdx.y;
  const int ce = cnt[e];
  const int off = woff[e];
  const int tmode = pm[0];
  __shared__ unsigned short As[2][64][32];      // 8 KB
  __shared__ unsigned short Bst[2][4 * PSTR];   // ~8.4 KB
  const int tid = threadIdx.x;
  const int w = tid >> 6, l = tid & 63;
  // A staging (common)
  const int row0 = tid >> 2;
  int gr = mt * 64 + row0; if (gr >= ce) gr = ce - 1;
  const size_t abase = (size_t)(off + gr) * HH + (size_t)(((tid & 3) ^ ((row0 >> 1) & 3)) * 8);
  const int aoff = tid * 8;
  const int n0 = nt * 64;
  const int wm = (w >> 1) * 32, wn = (w & 1) * 32;
  const int lr = l & 15, kg = l >> 4;
  const f32x4 zero = {0.f, 0.f, 0.f, 0.f};
  f32x4 acc[2][2];
  #pragma unroll
  for (int a = 0; a < 2; ++a)
    #pragma unroll
    for (int b = 0; b < 2; ++b) acc[a][b] = zero;

  if (tmode < 3) {
    // ---------- fused path ----------
    const int cA = pm[1], cK = pm[2];
    const float* srcD = bdown + (size_t)e * HH * DD + n0;
    int bgl[2], bwr[2];
    #pragma unroll
    for (int s = 0; s < 2; ++s) {
      int idx = s * 256 + tid;
      int k = idx >> 4;
      bgl[s] = k * DD + (idx & 15) * 4;
      bwr[s] = ((idx >> 2) & 3) * PSTR + k * 16 + (idx & 3) * 4;
    }
    const int tbadd = cA * lr + cK * kg;
    const int tb0 = ((w & 1) * 2) * PSTR + tbadd;
    const int tb1 = tb0 + PSTR;
    float4 rd[2];
    #pragma unroll
    for (int s = 0; s < 2; ++s) rd[s] = *reinterpret_cast<const float4*>(srcD + bgl[s]);
    gl_lds16(hid + abase, &As[0][0][0] + aoff);
    #pragma unroll
    for (int s = 0; s < 2; ++s) {
      ushort4 o = { f2bf(rd[s].x), f2bf(rd[s].y), f2bf(rd[s].z), f2bf(rd[s].w) };
      *reinterpret_cast<ushort4*>(&Bst[0][bwr[s]]) = o;
    }
    __syncthreads();
    int buf = 0;
    for (int kt = 0; kt < HH / 32; ++kt) {
      const int nxt = kt + 1;
      const bool more = nxt < HH / 32;
      if (more) {
        const size_t g = (size_t)nxt * (32 * DD);
        #pragma unroll
        for (int s = 0; s < 2; ++s)
          rd[s] = *reinterpret_cast<const float4*>(srcD + g + bgl[s]);
        gl_lds16(hid + abase + nxt * 32, &As[buf ^ 1][0][0] + aoff);
      }
      bf16x8 av[2];
      #pragma unroll
      for (int fm = 0; fm < 2; ++fm) {
        int row = wm + fm * 16 + lr;
        int c = kg ^ ((row >> 1) & 3);
        av[fm] = *reinterpret_cast<const bf16x8*>(&As[buf][row][c * 8]);
      }
      bf16x8 bv0 = trfrag(&Bst[buf][0] + tb0);
      bf16x8 bv1 = trfrag(&Bst[buf][0] + tb1);
      asm volatile("s_waitcnt lgkmcnt(0)" ::: "memory");
      __builtin_amdgcn_sched_barrier(0);
      #pragma unroll
      for (int fm = 0; fm < 2; ++fm) {
        acc[fm][0] = __builtin_amdgcn_mfma_f32_16x16x32_bf16(av[fm], bv0, acc[fm][0], 0, 0, 0);
        acc[fm][1] = __builtin_amdgcn_mfma_f32_16x16x32_bf16(av[fm], bv1, acc[fm][1], 0, 0, 0);
      }
      if (more) {
        #pragma unroll
        for (int s = 0; s < 2; ++s) {
          ushort4 o = { f2bf(rd[s].x), f2bf(rd[s].y), f2bf(rd[s].z), f2bf(rd[s].w) };
          *reinterpret_cast<ushort4*>(&Bst[buf ^ 1][bwr[s]]) = o;
        }
      }
      __syncthreads();
      buf ^= 1;
    }
  } else {
    // ---------- fallback path: pre-transposed bf16 wdT ----------
    const int nrow = tid >> 2;
    const int gB = (tid & 3) ^ ((nrow >> 1) & 3);
    const size_t bbase = ((size_t)e * DD + n0 + nrow) * HH + gB * 8;
    const int boff = tid * 8;
    gl_lds16(hid + abase, &As[0][0][0] + aoff);
    gl_lds16(wdT + bbase, &Bst[0][0] + boff);
    __syncthreads();
    int buf = 0;
    for (int kt = 0; kt < HH / 32; ++kt) {
      const int nxt = kt + 1;
      if (nxt < HH / 32) {
        gl_lds16(hid + abase + nxt * 32, &As[buf ^ 1][0][0] + aoff);
        gl_lds16(wdT + bbase + nxt * 32, &Bst[buf ^ 1][0] + boff);
      }
      bf16x8 av[2], bv[2];
      #pragma unroll
      for (int fm = 0; fm < 2; ++fm) {
        int row = wm + fm * 16 + lr;
        int c = kg ^ ((row >> 1) & 3);
        av[fm] = *reinterpret_cast<const bf16x8*>(&As[buf][row][c * 8]);
      }
      #pragma unroll
      for (int fn = 0; fn < 2; ++fn) {
        int row = wn + fn * 16 + lr;
        int c = kg ^ ((row >> 1) & 3);
        bv[fn] = *reinterpret_cast<const bf16x8*>(&Bst[buf][row * 32 + c * 8]);
      }
      #pragma unroll
      for (int fm = 0; fm < 2; ++fm)
        #pragma unroll
        for (int fn = 0; fn < 2; ++fn)
          acc[fm][fn] = __builtin_amdgcn_mfma_f32_16x16x32_bf16(av[fm], bv[fn], acc[fm][fn], 0, 0, 0);
      __syncthreads();
      buf ^= 1;
    }
  }
  // ---------- epilogue (common) ----------
  #pragma unroll
  for (int fn = 0; fn < 2; ++fn) {
    const int ng = n0 + wn + fn * 16 + lr;
    #pragma unroll
    for (int fm = 0; fm < 2; ++fm) {
      #pragma unroll
      for (int jj = 0; jj < 4; ++jj) {
        int m = mt * 64 + wm + fm * 16 + kg * 4 + jj;
        if (m < ce)
          op[(size_t)(off + m) * DD + ng] = f2bf(acc[fm][fn][jj]);
      }
    }
  }
}

// ---------------- combine + RMSNorm ----------------
__global__ __launch_bounds__(256) void k_norm(
    const unsigned short* __restrict__ op, const int* __restrict__ woff,
    const int* __restrict__ rec, const float* __restrict__ wrec,
    const float* __restrict__ nw, float* __restrict__ out) {
  const int t = blockIdx.x;
  const int tid = threadIdx.x;
  __shared__ float red[4];
  const int e1 = rec[t * 4 + 0], p1 = rec[t * 4 + 1];
  const int e2 = rec[t * 4 + 2], p2 = rec[t * 4 + 3];
  const float w1 = wrec[t * 2 + 0], w2 = wrec[t * 2 + 1];
  const unsigned short* pa = op + (size_t)(woff[e1] + p1) * DD;
  const unsigned short* pb = op + (size_t)(woff[e2] + p2) * DD;
  float v[4]; float ss = 0.f;
  #pragma unroll
  for (int q = 0; q < 4; ++q) {
    int i = q * 256 + tid;
    v[q] = w1 * bf2f(pa[i]) + w2 * bf2f(pb[i]);
    ss += v[q] * v[q];
  }
  #pragma unroll
  for (int o = 32; o > 0; o >>= 1) ss += __shfl_xor(ss, o);
  if ((tid & 63) == 0) red[tid >> 6] = ss;
  __syncthreads();
  const float tot = red[0] + red[1] + red[2] + red[3];
  const float scl = rsqrtf(tot * (1.f / DD) + 1e-6f);
  #pragma unroll
  for (int q = 0; q < 4; ++q) {
    int i = q * 256 + tid;
    out[(size_t)t * DD + i] = v[q] * scl * nw[i];
  }
}

extern "C" void kernel_launch(void* const* d_in, const int* in_sizes, int n_in,
                              void* d_out, int out_size, void* d_ws, size_t ws_size,
                              hipStream_t stream) {
  const float* x      = (const float*)d_in[0];
  const float* rw     = (const float*)d_in[1];
  const float* rb     = (const float*)d_in[2];
  const float* bmag   = (const float*)d_in[3];
  const float* bfreq  = (const float*)d_in[4];
  const float* bphase = (const float*)d_in[5];
  const float* bdown  = (const float*)d_in[6];
  const float* nw     = (const float*)d_in[7];
  float* out = (float*)d_out;
  char* ws = (char*)d_ws;
  const size_t MB = 1024 * 1024;
  int*   cnt    = (int*)(ws + 0);          // 16 int
  int*   work1  = (int*)(ws + 128);        // WM128*2 int
  int*   work2  = (int*)(ws + 1024);       // WM64*2 int
  int*   woff   = (int*)(ws + 2048);       // 16 int
  int*   pm     = (int*)(ws + 3072);       // {mode, cA, cK}
  int*   list   = (int*)(ws + 4096);       // 16*2048 int
  int*   rec    = (int*)(ws + 139264);     // 2048*4 int
  float* wrec   = (float*)(ws + 172032);   // 2048*2 f32
  unsigned short* xbf = (unsigned short*)(ws + 1 * MB);    // 4 MB
  unsigned short* hid = (unsigned short*)(ws + 5 * MB);    // 16 MB
  unsigned short* op  = (unsigned short*)(ws + 21 * MB);   // 8 MB
  unsigned short* wmT = (unsigned short*)(ws + 32 * MB);   // 64 MB (fallback; reused by wdT)
  unsigned short* wfT = (unsigned short*)(ws + 96 * MB);   // 64 MB (fallback)
  unsigned short* wdT = wmT;                               // alias (fallback, after k_up)

  hipMemsetAsync(cnt, 0, 64, stream);
  k_probe<<<1, 64, 0, stream>>>(pm);
  k_cvt_x<<<1024, 256, 0, stream>>>(x, xbf);
  k_router<<<TT, 256, 0, stream>>>(x, rw, rb, cnt, list, rec, wrec);
  k_sched<<<1, 64, 0, stream>>>(cnt, work1, work2, woff);
  // fallback-only transposes (early-exit if fused path verified)
  k_trans<<<dim3(HH / 64, DD / 64, 32), 256, 0, stream>>>(bmag, bfreq, wmT, wfT, DD, HH, pm);
  k_up<<<dim3(WM128, HH / 64), 256, 0, stream>>>(xbf, bmag, bfreq, wmT, wfT, bphase,
                                                 cnt, list, work1, woff, pm, hid);
  k_trans<<<dim3(DD / 64, HH / 64, 16), 256, 0, stream>>>(bdown, bdown, wdT, wdT, HH, DD, pm);
  k_down<<<dim3(WM64, DD / 64), 256, 0, stream>>>(hid, bdown, wdT, cnt, work2, woff, pm, op);
  k_norm<<<TT, 256, 0, stream>>>(op, woff, rec, wrec, nw, out);
}